// Round 1
// baseline (437.324 us; speedup 1.0000x reference)
//
#include <hip/hip_runtime.h>
#include <math.h>

// Problem constants (from reference setup_inputs)
#define BB 8
#define HH 16
#define LQ 128
#define LC 4096
#define DD 1024
#define ROWS (HH * LQ)            // 2048 rows to reduce per (b, lc)
#define R_SLABS 32
#define ROWS_PER_SLAB (ROWS / R_SLABS)  // 64
#define COL_TILES 4               // 1024 cols per tile (256 threads x float4)
#define KTOP 5
#define EPSF 1e-8f

// ---------------------------------------------------------------------------
// K1: partial column sums of cross_attn_weights [B][H][Lq][Lc] over (H,Lq).
// grid = B * COL_TILES * R_SLABS = 1024 blocks, 256 threads, float4/thread.
// Deterministic (no atomics) so top-k selection is stable across replays.
// ---------------------------------------------------------------------------
__global__ __launch_bounds__(256) void k1_col_partials(
    const float* __restrict__ attn, float* __restrict__ partials) {
    int blk = blockIdx.x;
    int r = blk % R_SLABS;
    int t = blk / R_SLABS;
    int ct = t % COL_TILES;
    int b = t / COL_TILES;
    int col = ct * 1024 + threadIdx.x * 4;

    const float4* src = (const float4*)(attn + (size_t)b * ROWS * LC
                                             + (size_t)r * ROWS_PER_SLAB * LC + col);
    float4 acc = make_float4(0.f, 0.f, 0.f, 0.f);
#pragma unroll 8
    for (int m = 0; m < ROWS_PER_SLAB; ++m) {
        float4 v = src[(size_t)m * (LC / 4)];
        acc.x += v.x; acc.y += v.y; acc.z += v.z; acc.w += v.w;
    }
    float4* dst = (float4*)(partials + (size_t)r * BB * LC + (size_t)b * LC + col);
    *dst = acc;
}

// ---------------------------------------------------------------------------
// K2: reduce R_SLABS partials -> avg (really: column SUM; ranking-invariant).
// grid = B*LC/256 = 128 blocks.
// ---------------------------------------------------------------------------
__global__ __launch_bounds__(256) void k2_reduce_avg(
    const float* __restrict__ partials, float* __restrict__ avg) {
    int g = blockIdx.x * 256 + threadIdx.x;   // g in [0, B*LC)
    float s = 0.f;
#pragma unroll
    for (int r = 0; r < R_SLABS; ++r)
        s += partials[(size_t)r * BB * LC + g];
    avg[g] = s;
}

// ---------------------------------------------------------------------------
// K3: q_vec[b][d] = mean over Lq of question_emb[b][row][d].
// grid = B*D/256 = 32 blocks. Consecutive threads -> consecutive d: coalesced.
// ---------------------------------------------------------------------------
__global__ __launch_bounds__(256) void k3_qmean(
    const float* __restrict__ q, float* __restrict__ qv) {
    int g = blockIdx.x * 256 + threadIdx.x;   // g in [0, B*D)
    int b = g / DD;
    int d = g % DD;
    const float* p = q + (size_t)b * LQ * DD + d;
    float s = 0.f;
#pragma unroll 8
    for (int row = 0; row < LQ; ++row)
        s += p[(size_t)row * DD];
    qv[g] = s * (1.0f / LQ);
}

// ---------------------------------------------------------------------------
// K4: per-batch finalize. grid = B blocks of 256 threads.
//  - top-5 of avg[b][:] via 5 rounds of block-argmax (low-index tie-break,
//    matching jax.lax.top_k)
//  - cosine sim of q_vec[b] vs the 5 gathered context rows
//  - atomicAdd mean(1-sim)/ (B*K) into *out (out pre-zeroed by memsetAsync)
// ---------------------------------------------------------------------------
__global__ __launch_bounds__(256) void k4_finalize(
    const float* __restrict__ avg, const float* __restrict__ qv,
    const float* __restrict__ ctx, float* __restrict__ out) {
    __shared__ float s_avg[LC];       // 16 KB
    __shared__ float red[256];
    __shared__ float red2[256];
    __shared__ int   redi[256];
    __shared__ int   s_topidx[KTOP];
    __shared__ float s_qn;

    int b = blockIdx.x;
    int tid = threadIdx.x;

    // load avg column-sums into LDS
#pragma unroll
    for (int j = 0; j < LC / 256; ++j) {
        int c = tid + j * 256;
        s_avg[c] = avg[(size_t)b * LC + c];
    }
    __syncthreads();

    // top-5 via repeated block argmax, masking winners
    for (int kk = 0; kk < KTOP; ++kk) {
        float best = -3.0e38f;
        int besti = LC;
#pragma unroll
        for (int j = 0; j < LC / 256; ++j) {
            int c = tid + j * 256;
            float v = s_avg[c];
            if (v > best || (v == best && c < besti)) { best = v; besti = c; }
        }
        red[tid] = best; redi[tid] = besti;
        __syncthreads();
        for (int s = 128; s > 0; s >>= 1) {
            if (tid < s) {
                float ov = red[tid + s]; int oi = redi[tid + s];
                if (ov > red[tid] || (ov == red[tid] && oi < redi[tid])) {
                    red[tid] = ov; redi[tid] = oi;
                }
            }
            __syncthreads();
        }
        if (tid == 0) {
            s_topidx[kk] = redi[0];
            s_avg[redi[0]] = -3.0e38f;   // mask for next round
        }
        __syncthreads();
    }

    // q_vec fragment (4 floats/thread) + ||q||^2 reduction
    float4 q4 = *((const float4*)(qv + (size_t)b * DD + tid * 4));
    float qq = q4.x * q4.x + q4.y * q4.y + q4.z * q4.z + q4.w * q4.w;
    red[tid] = qq;
    __syncthreads();
    for (int s = 128; s > 0; s >>= 1) {
        if (tid < s) red[tid] += red[tid + s];
        __syncthreads();
    }
    if (tid == 0) s_qn = fmaxf(sqrtf(red[0]), EPSF);
    __syncthreads();

    float loss = 0.f;  // meaningful on tid 0 only
    for (int kk = 0; kk < KTOP; ++kk) {
        int idx = s_topidx[kk];
        float4 c4 = *((const float4*)(ctx + (size_t)b * LC * DD + (size_t)idx * DD + tid * 4));
        float dpart = q4.x * c4.x + q4.y * c4.y + q4.z * c4.z + q4.w * c4.w;
        float cpart = c4.x * c4.x + c4.y * c4.y + c4.z * c4.z + c4.w * c4.w;
        red[tid] = dpart; red2[tid] = cpart;
        __syncthreads();
        for (int s = 128; s > 0; s >>= 1) {
            if (tid < s) { red[tid] += red[tid + s]; red2[tid] += red2[tid + s]; }
            __syncthreads();
        }
        if (tid == 0) {
            float cn = fmaxf(sqrtf(red2[0]), EPSF);
            loss += 1.0f - red[0] / (s_qn * cn);
        }
        __syncthreads();
    }
    if (tid == 0) {
        atomicAdd(out, loss * (1.0f / (BB * KTOP)));
    }
}

extern "C" void kernel_launch(void* const* d_in, const int* in_sizes, int n_in,
                              void* d_out, int out_size, void* d_ws, size_t ws_size,
                              hipStream_t stream) {
    const float* q    = (const float*)d_in[0];  // question_emb   [8,128,1024]
    const float* ctx  = (const float*)d_in[1];  // context_emb    [8,4096,1024]
    const float* attn = (const float*)d_in[2];  // cross_attn     [8,16,128,4096]
    float* out = (float*)d_out;

    // ws layout (floats):
    //   partials: R_SLABS*B*LC = 1,048,576  (4 MB)
    //   avg:      B*LC         =    32,768  (128 KB)
    //   qv:       B*D          =     8,192  (32 KB)
    float* partials = (float*)d_ws;
    float* avg = partials + (size_t)R_SLABS * BB * LC;
    float* qv  = avg + (size_t)BB * LC;

    // d_out is re-poisoned to 0xAA before every timed launch -> zero it here.
    hipMemsetAsync(d_out, 0, sizeof(float), stream);

    k1_col_partials<<<BB * COL_TILES * R_SLABS, 256, 0, stream>>>(attn, partials);
    k2_reduce_avg<<<(BB * LC) / 256, 256, 0, stream>>>(partials, avg);
    k3_qmean<<<(BB * DD) / 256, 256, 0, stream>>>(q, qv);
    k4_finalize<<<BB, 256, 0, stream>>>(avg, qv, ctx, out);
}

// Round 2
// 423.613 us; speedup vs baseline: 1.0324x; 1.0324x over previous
//
#include <hip/hip_runtime.h>
#include <math.h>

// Problem constants (from reference setup_inputs)
#define BB 8
#define HH 16
#define LQ 128
#define LC 4096
#define DD 1024
#define ROWS (HH * LQ)            // 2048 rows to reduce per (b, lc)
#define R_SLABS 32
#define ROWS_PER_SLAB (ROWS / R_SLABS)  // 64
#define COL_TILES 4               // 1024 cols per tile (256 threads x float4)
#define KTOP 5
#define EPSF 1e-8f

// ---------------------------------------------------------------------------
// K1: partial column sums of cross_attn_weights [B][H][Lq][Lc] over (H,Lq).
// grid = B * COL_TILES * R_SLABS = 1024 blocks, 256 threads, float4/thread.
// Deterministic (no atomics) so top-k selection is stable across replays.
// Also zeroes *out (stream order puts this before K4's atomicAdd).
// ---------------------------------------------------------------------------
__global__ __launch_bounds__(256) void k1_col_partials(
    const float* __restrict__ attn, float* __restrict__ partials,
    float* __restrict__ out) {
    if (blockIdx.x == 0 && threadIdx.x == 0) *out = 0.0f;

    int blk = blockIdx.x;
    int r = blk % R_SLABS;
    int t = blk / R_SLABS;
    int ct = t % COL_TILES;
    int b = t / COL_TILES;
    int col = ct * 1024 + threadIdx.x * 4;

    const float4* src = (const float4*)(attn + (size_t)b * ROWS * LC
                                             + (size_t)r * ROWS_PER_SLAB * LC + col);
    float4 acc = make_float4(0.f, 0.f, 0.f, 0.f);
#pragma unroll 8
    for (int m = 0; m < ROWS_PER_SLAB; ++m) {
        float4 v = src[(size_t)m * (LC / 4)];
        acc.x += v.x; acc.y += v.y; acc.z += v.z; acc.w += v.w;
    }
    float4* dst = (float4*)(partials + (size_t)r * BB * LC + (size_t)b * LC + col);
    *dst = acc;
}

// ---------------------------------------------------------------------------
// K23: fused. Blocks [0,128): avg[g] = sum_r partials[r][g]  (column SUM —
// ranking-invariant vs the reference's mean). Blocks [128,160): q_vec mean.
// ---------------------------------------------------------------------------
__global__ __launch_bounds__(256) void k23_reduce(
    const float* __restrict__ partials, const float* __restrict__ q,
    float* __restrict__ avg, float* __restrict__ qv) {
    int blk = blockIdx.x;
    if (blk < (BB * LC) / 256) {
        int g = blk * 256 + threadIdx.x;   // g in [0, B*LC)
        float s = 0.f;
#pragma unroll
        for (int r = 0; r < R_SLABS; ++r)
            s += partials[(size_t)r * BB * LC + g];
        avg[g] = s;
    } else {
        int g = (blk - (BB * LC) / 256) * 256 + threadIdx.x;  // [0, B*D)
        int b = g / DD;
        int d = g % DD;
        const float* p = q + (size_t)b * LQ * DD + d;
        float s = 0.f;
#pragma unroll 8
        for (int row = 0; row < LQ; ++row)
            s += p[(size_t)row * DD];
        qv[g] = s * (1.0f / LQ);
    }
}

// ---------------------------------------------------------------------------
// K4: per-batch finalize. grid = B blocks of 256 threads (4 waves).
//  - avg row held in registers (16 vals/thread, col = j*256 + tid)
//  - top-5 via 5 rounds of wave-shuffle argmax (low-index tie-break, matching
//    jax.lax.top_k); one __syncthreads per round
//  - 11 reductions (5 dots, 5 ctx norms, q norm) batched into ONE shuffle pass
//  - atomicAdd mean(1-sim)/(B*K) into *out (out zeroed by K1)
// ---------------------------------------------------------------------------
__global__ __launch_bounds__(256) void k4_finalize(
    const float* __restrict__ avg, const float* __restrict__ qv,
    const float* __restrict__ ctx, float* __restrict__ out) {
    __shared__ float swv[4];
    __shared__ int   swi[4];
    __shared__ int   s_win;
    __shared__ int   s_top[KTOP];
    __shared__ float sred[4][11];

    int b = blockIdx.x;
    int tid = threadIdx.x;
    int lane = tid & 63;
    int wave = tid >> 6;

    // avg row in registers; col = j*256 + tid
    float v[16];
#pragma unroll
    for (int j = 0; j < 16; ++j)
        v[j] = avg[(size_t)b * LC + j * 256 + tid];

    // ---- top-5: 5 rounds of block argmax via shuffles ----
    for (int kk = 0; kk < KTOP; ++kk) {
        float bv = v[0];
        int bj = 0;
#pragma unroll
        for (int j = 1; j < 16; ++j)
            if (v[j] > bv) { bv = v[j]; bj = j; }   // strict > prefers lower col
        int bc = bj * 256 + tid;

        for (int off = 32; off > 0; off >>= 1) {
            float ov = __shfl_down(bv, off);
            int   oc = __shfl_down(bc, off);
            if (ov > bv || (ov == bv && oc < bc)) { bv = ov; bc = oc; }
        }
        if (lane == 0) { swv[wave] = bv; swi[wave] = bc; }
        __syncthreads();
        if (tid == 0) {
            float fv = swv[0]; int fc = swi[0];
#pragma unroll
            for (int w = 1; w < 4; ++w)
                if (swv[w] > fv || (swv[w] == fv && swi[w] < fc)) { fv = swv[w]; fc = swi[w]; }
            s_top[kk] = fc;
            s_win = fc;
        }
        __syncthreads();
        int wc = s_win;
        if ((wc & 255) == tid) v[wc >> 8] = -3.0e38f;  // mask winner in its owner's reg
        // no barrier needed here: next round's swv write is already ordered
        // after tid0's swv read by the sync above
    }

    // ---- cosine: batch 11 reductions (5 dots, 5 c-norms, 1 q-norm) ----
    const float4 q4 = *((const float4*)(qv + (size_t)b * DD + tid * 4));
    float acc[11];
    acc[10] = q4.x * q4.x + q4.y * q4.y + q4.z * q4.z + q4.w * q4.w;
#pragma unroll
    for (int kk = 0; kk < KTOP; ++kk) {
        const float4 c4 = *((const float4*)(ctx + (size_t)b * LC * DD
                                            + (size_t)s_top[kk] * DD + tid * 4));
        acc[kk]        = q4.x * c4.x + q4.y * c4.y + q4.z * c4.z + q4.w * c4.w;
        acc[5 + kk]    = c4.x * c4.x + c4.y * c4.y + c4.z * c4.z + c4.w * c4.w;
    }
    for (int off = 32; off > 0; off >>= 1) {
#pragma unroll
        for (int i = 0; i < 11; ++i)
            acc[i] += __shfl_down(acc[i], off);
    }
    if (lane == 0) {
#pragma unroll
        for (int i = 0; i < 11; ++i) sred[wave][i] = acc[i];
    }
    __syncthreads();
    if (tid == 0) {
        float t[11];
#pragma unroll
        for (int i = 0; i < 11; ++i)
            t[i] = sred[0][i] + sred[1][i] + sred[2][i] + sred[3][i];
        float qn = fmaxf(sqrtf(t[10]), EPSF);
        float loss = 0.f;
#pragma unroll
        for (int kk = 0; kk < KTOP; ++kk) {
            float cn = fmaxf(sqrtf(t[5 + kk]), EPSF);
            loss += 1.0f - t[kk] / (qn * cn);
        }
        atomicAdd(out, loss * (1.0f / (BB * KTOP)));
    }
}

extern "C" void kernel_launch(void* const* d_in, const int* in_sizes, int n_in,
                              void* d_out, int out_size, void* d_ws, size_t ws_size,
                              hipStream_t stream) {
    const float* q    = (const float*)d_in[0];  // question_emb   [8,128,1024]
    const float* ctx  = (const float*)d_in[1];  // context_emb    [8,4096,1024]
    const float* attn = (const float*)d_in[2];  // cross_attn     [8,16,128,4096]
    float* out = (float*)d_out;

    // ws layout (floats):
    //   partials: R_SLABS*B*LC = 1,048,576  (4 MB)
    //   avg:      B*LC         =    32,768  (128 KB)
    //   qv:       B*D          =     8,192  (32 KB)
    float* partials = (float*)d_ws;
    float* avg = partials + (size_t)R_SLABS * BB * LC;
    float* qv  = avg + (size_t)BB * LC;

    k1_col_partials<<<BB * COL_TILES * R_SLABS, 256, 0, stream>>>(attn, partials, out);
    k23_reduce<<<(BB * LC) / 256 + (BB * DD) / 256, 256, 0, stream>>>(partials, q, avg, qv);
    k4_finalize<<<BB, 256, 0, stream>>>(avg, qv, ctx, out);
}